// Round 1
// baseline (1887.139 us; speedup 1.0000x reference)
//
#include <hip/hip_runtime.h>
#include <math.h>

#define N_NODES 100000
#define DIM 64

// Phase 1: scatter-add edge embeddings + degrees into node tables.
// Thread = (edge, dim). 128M f32 atomics into 25.6MB (L2/L3-resident).
__global__ void scatter_kernel(const float* __restrict__ edge_emb,
                               const int* __restrict__ idx,
                               float* __restrict__ node_sum,
                               float* __restrict__ deg,
                               int n_edges) {
    long long gid = (long long)blockIdx.x * blockDim.x + threadIdx.x;
    if (gid >= (long long)n_edges * DIM) return;
    int e = (int)(gid >> 6);
    int d = (int)(gid & 63);
    float val = edge_emb[gid];
    int u = idx[2 * e];
    int v = idx[2 * e + 1];
    atomicAdd(&node_sum[(long long)u * DIM + d], val);
    atomicAdd(&node_sum[(long long)v * DIM + d], val);
    if (d == 0) {
        atomicAdd(&deg[u], 1.f);
        atomicAdd(&deg[v], 1.f);
    }
}

// Phase 2: per-edge exclusive means, two 64x64 matmuls, gate, blend.
// Wave = edge, lane = output dim. Wf/Wb columns live in registers
// (128 VGPR); agg vectors staged in wave-private LDS rows, read back
// as float4 broadcasts (all lanes same address -> conflict-free).
__global__ __launch_bounds__(256) void fused_edge_kernel(
    const float* __restrict__ edge_emb,
    const int* __restrict__ idx,
    const float* __restrict__ node_sum,
    const float* __restrict__ deg,
    const float* __restrict__ Wf, const float* __restrict__ bf,
    const float* __restrict__ Wb, const float* __restrict__ bb,
    const float* __restrict__ Wg, const float* __restrict__ bg,
    float* __restrict__ out, int n_edges)
{
    __shared__ __align__(16) float sU[4][64];
    __shared__ __align__(16) float sV[4][64];
    const int lane = threadIdx.x & 63;
    const int w = threadIdx.x >> 6;

    // Weight columns into registers (amortized over many edges/wave).
    float wf[64], wb[64];
#pragma unroll
    for (int k = 0; k < 64; ++k) {
        wf[k] = Wf[k * 64 + lane];
        wb[k] = Wb[k * 64 + lane];
    }
    const float bfv = bf[lane];
    const float bbv = bb[lane];
    const float wgv = Wg[lane];
    const float bgv = bg[0];

    const int nwaves = gridDim.x * 4;
    for (int e = blockIdx.x * 4 + w; e < n_edges; e += nwaves) {
        float ev = edge_emb[(long long)e * 64 + lane];
        int u = idx[2 * e];
        int v = idx[2 * e + 1];
        float du = deg[u];
        float dv = deg[v];
        float invu = (du > 1.f) ? 1.f / (du - 1.f) : 0.f;
        float invv = (dv > 1.f) ? 1.f / (dv - 1.f) : 0.f;
        sU[w][lane] = (node_sum[(long long)u * 64 + lane] - ev) * invu;
        sV[w][lane] = (node_sum[(long long)v * 64 + lane] - ev) * invv;
        // wave-private LDS rows: no __syncthreads needed, the wave's own
        // lgkmcnt ordering covers the write->read dependency.
        float accf = 0.f, accb = 0.f;
        const float4* pu = (const float4*)sU[w];
        const float4* pv = (const float4*)sV[w];
#pragma unroll
        for (int kk = 0; kk < 16; ++kk) {
            float4 au = pu[kk];
            float4 av = pv[kk];
            accf = fmaf(au.x, wf[4 * kk + 0], accf);
            accb = fmaf(av.x, wb[4 * kk + 0], accb);
            accf = fmaf(au.y, wf[4 * kk + 1], accf);
            accb = fmaf(av.y, wb[4 * kk + 1], accb);
            accf = fmaf(au.z, wf[4 * kk + 2], accf);
            accb = fmaf(av.z, wb[4 * kk + 2], accb);
            accf = fmaf(au.w, wf[4 * kk + 3], accf);
            accb = fmaf(av.w, wb[4 * kk + 3], accb);
        }
        float af = accf + bfv;
        float ab = accb + bbv;
        // gate = sigmoid(dot(af+ab, Wg) + bg), wave-wide reduction
        float s = (af + ab) * wgv;
#pragma unroll
        for (int off = 32; off > 0; off >>= 1) s += __shfl_xor(s, off);
        float gate = 1.f / (1.f + __expf(-(s + bgv)));
        out[(long long)e * 64 + lane] = fmaf(gate, af - ab, ab);
    }
}

extern "C" void kernel_launch(void* const* d_in, const int* in_sizes, int n_in,
                              void* d_out, int out_size, void* d_ws, size_t ws_size,
                              hipStream_t stream) {
    const float* edge_emb = (const float*)d_in[0];
    const float* Wf = (const float*)d_in[1];
    const float* bf = (const float*)d_in[2];
    const float* Wb = (const float*)d_in[3];
    const float* bb = (const float*)d_in[4];
    const float* Wg = (const float*)d_in[5];
    const float* bg = (const float*)d_in[6];
    const int* idx = (const int*)d_in[7];
    float* out = (float*)d_out;

    const int n_edges = in_sizes[7] / 2;

    float* node_sum = (float*)d_ws;                          // N_NODES*64 floats
    float* deg = node_sum + (long long)N_NODES * DIM;        // N_NODES floats

    // zero node_sum + deg (ws is poisoned 0xAA before every call)
    size_t zero_bytes = ((size_t)N_NODES * DIM + N_NODES) * sizeof(float);
    hipMemsetAsync(d_ws, 0, zero_bytes, stream);

    long long total = (long long)n_edges * DIM;
    int blocks1 = (int)((total + 255) / 256);
    scatter_kernel<<<blocks1, 256, 0, stream>>>(edge_emb, idx, node_sum, deg, n_edges);

    int blocks2 = 4096;  // grid-stride: ~61 edges/wave, amortizes weight preamble
    fused_edge_kernel<<<blocks2, 256, 0, stream>>>(
        edge_emb, idx, node_sum, deg, Wf, bf, Wb, bb, Wg, bg, out, n_edges);
}

// Round 2
// 879.676 us; speedup vs baseline: 2.1453x; 2.1453x over previous
//
#include <hip/hip_runtime.h>
#include <hip/hip_bf16.h>
#include <math.h>

#define N_NODES 100000
#define DIM 64
#define BATCH 16        // edges per wave-batch = one MFMA M-tile
#define LDS_PITCH 72    // bf16/row: 144B rows -> 16B aligned, ~2-way banks on b128 reads

typedef __attribute__((ext_vector_type(8))) short short8;
typedef __attribute__((ext_vector_type(4))) float floatx4;

__device__ __forceinline__ short f2bf(float x) {           // RNE f32->bf16
    unsigned u = __float_as_uint(x);
    u += 0x7FFF + ((u >> 16) & 1);
    return (short)(u >> 16);
}
__device__ __forceinline__ float bf2f(unsigned short b) {
    return __uint_as_float(((unsigned)b) << 16);
}

// Phase 1: scatter-add edge embeddings into bf16 node table with packed
// bf16x2 HW atomics (global_atomic_pk_add_bf16): 64M pk-atomics instead of
// 128M dword atomics. Thread = (edge, dim-pair).
__global__ __launch_bounds__(256) void scatter_kernel(
    const float* __restrict__ edge_emb, const int* __restrict__ idx,
    __hip_bfloat162* __restrict__ node_sum, float* __restrict__ deg, int n_edges)
{
    long long gid = (long long)blockIdx.x * blockDim.x + threadIdx.x;
    if (gid >= (long long)n_edges * 32) return;
    int e = (int)(gid >> 5);
    int p = (int)(gid & 31);
    float2 ev = ((const float2*)edge_emb)[gid];   // flat pair index == gid
    int2 uv = ((const int2*)idx)[e];
    union { unsigned u32; __hip_bfloat162 h; } cv;
    cv.u32 = (unsigned)(unsigned short)f2bf(ev.x)
           | ((unsigned)(unsigned short)f2bf(ev.y) << 16);
    unsafeAtomicAdd(&node_sum[(size_t)uv.x * 32 + p], cv.h);
    unsafeAtomicAdd(&node_sum[(size_t)uv.y * 32 + p], cv.h);
    if (p == 0) {
        unsafeAtomicAdd(&deg[uv.x], 1.f);
        unsafeAtomicAdd(&deg[uv.y], 1.f);
    }
}

// Phase 2: wave-independent MFMA pipeline. Each wave: stage 16 edges of
// aggU/aggV (bf16) into its private LDS slab, run 16x64x64 GEMM vs Wf/Wb
// held as persistent B-fragments in VGPRs, gate+blend epilogue.
// mfma_f32_16x16x32_bf16 layouts (m89/m120 verified):
//   A[m=lane&15][k=(lane>>4)*8+j], B[k=(lane>>4)*8+j][n=lane&15],
//   C[row=(lane>>4)*4+reg][col=lane&15]
__global__ __launch_bounds__(256) void fused_edge_kernel(
    const float* __restrict__ edge_emb,
    const int* __restrict__ idx,
    const unsigned short* __restrict__ node_sum,   // bf16 bits
    const float* __restrict__ deg,
    const float* __restrict__ Wf, const float* __restrict__ bf,
    const float* __restrict__ Wb, const float* __restrict__ bb,
    const float* __restrict__ Wg, const float* __restrict__ bg,
    float* __restrict__ out, int n_edges)
{
    __shared__ short lds[4][2][BATCH * LDS_PITCH];   // [wave][U/V]
    const int lane = threadIdx.x & 63;
    const int l15 = lane & 15;
    const int q = lane >> 4;
    const int wslot = threadIdx.x >> 6;
    const int wid = __builtin_amdgcn_readfirstlane(blockIdx.x * 4 + wslot);
    const int nwaves = gridDim.x * 4;

    // Persistent B-fragments (bf16): 4 n-tiles x 2 k-tiles x 4 VGPR = 32 VGPR/matrix
    short8 bWf[4][2], bWb[4][2];
#pragma unroll
    for (int nt = 0; nt < 4; ++nt)
#pragma unroll
        for (int kt = 0; kt < 2; ++kt) {
            short8 f, g;
#pragma unroll
            for (int j = 0; j < 8; ++j) {
                int k = kt * 32 + q * 8 + j;
                int n = nt * 16 + l15;
                f[j] = f2bf(Wf[k * 64 + n]);
                g[j] = f2bf(Wb[k * 64 + n]);
            }
            bWf[nt][kt] = f;
            bWb[nt][kt] = g;
        }
    float bfv[4], bbv[4], wgv[4];
#pragma unroll
    for (int nt = 0; nt < 4; ++nt) {
        bfv[nt] = bf[nt * 16 + l15];
        bbv[nt] = bb[nt * 16 + l15];
        wgv[nt] = Wg[nt * 16 + l15];
    }
    const float bgv = bg[0];

    short* ldsU = lds[wslot][0];
    short* ldsV = lds[wslot][1];

    const int nbatches = n_edges / BATCH;   // E=1M divisible by 16
    for (int b = wid; b < nbatches; b += nwaves) {
        const int e0 = b * BATCH;
        // ---- stage 16 edges: independent iterations -> deep ILP on gathers
#pragma unroll
        for (int i = 0; i < BATCH; ++i) {
            const int e = e0 + i;                 // wave-uniform -> s_loads
            const int u = idx[2 * e];
            const int v = idx[2 * e + 1];
            const float du = deg[u];
            const float dv = deg[v];
            const float invu = (du > 1.f) ? 1.f / (du - 1.f) : 0.f;
            const float invv = (dv > 1.f) ? 1.f / (dv - 1.f) : 0.f;
            const float ev = edge_emb[(size_t)e * 64 + lane];
            const float nsu = bf2f(node_sum[(size_t)u * 64 + lane]);
            const float nsv = bf2f(node_sum[(size_t)v * 64 + lane]);
            ldsU[i * LDS_PITCH + lane] = f2bf((nsu - ev) * invu);
            ldsV[i * LDS_PITCH + lane] = f2bf((nsv - ev) * invv);
        }
        // wave-private LDS: same-wave write->read ordering via lgkmcnt (compiler)

        // ---- A fragments (16B-aligned b128 reads)
        short8 aU[2], aV[2];
#pragma unroll
        for (int kt = 0; kt < 2; ++kt) {
            const int off = l15 * LDS_PITCH + kt * 32 + q * 8;
            aU[kt] = *(const short8*)&ldsU[off];
            aV[kt] = *(const short8*)&ldsV[off];
        }

        // ---- GEMM: 16 MFMAs per 16 edges (1 MFMA-equivalent per edge)
        floatx4 cU[4], cV[4];
#pragma unroll
        for (int nt = 0; nt < 4; ++nt) {
            floatx4 z = {0.f, 0.f, 0.f, 0.f};
            z = __builtin_amdgcn_mfma_f32_16x16x32_bf16(aU[0], bWf[nt][0], z, 0, 0, 0);
            cU[nt] = __builtin_amdgcn_mfma_f32_16x16x32_bf16(aU[1], bWf[nt][1], z, 0, 0, 0);
            floatx4 z2 = {0.f, 0.f, 0.f, 0.f};
            z2 = __builtin_amdgcn_mfma_f32_16x16x32_bf16(aV[0], bWb[nt][0], z2, 0, 0, 0);
            cV[nt] = __builtin_amdgcn_mfma_f32_16x16x32_bf16(aV[1], bWb[nt][1], z2, 0, 0, 0);
        }

        // ---- epilogue: biases, gate dot (reduce over 16-lane col groups), blend
        float p[4] = {0.f, 0.f, 0.f, 0.f};
#pragma unroll
        for (int nt = 0; nt < 4; ++nt)
#pragma unroll
            for (int r = 0; r < 4; ++r) {
                float af = cU[nt][r] + bfv[nt];
                float ab = cV[nt][r] + bbv[nt];
                cU[nt][r] = af;
                cV[nt][r] = ab;
                p[r] = fmaf(af + ab, wgv[nt], p[r]);
            }
#pragma unroll
        for (int r = 0; r < 4; ++r) {
            float s = p[r];
            s += __shfl_xor(s, 1);
            s += __shfl_xor(s, 2);
            s += __shfl_xor(s, 4);
            s += __shfl_xor(s, 8);
            p[r] = 1.f / (1.f + __expf(-(s + bgv)));   // gate for edge e0+4q+r
        }
#pragma unroll
        for (int nt = 0; nt < 4; ++nt)
#pragma unroll
            for (int r = 0; r < 4; ++r) {
                const int e = e0 + q * 4 + r;          // C row = q*4 + r
                out[(size_t)e * 64 + nt * 16 + l15] =
                    fmaf(p[r], cU[nt][r] - cV[nt][r], cV[nt][r]);
            }
    }
}

extern "C" void kernel_launch(void* const* d_in, const int* in_sizes, int n_in,
                              void* d_out, int out_size, void* d_ws, size_t ws_size,
                              hipStream_t stream) {
    const float* edge_emb = (const float*)d_in[0];
    const float* Wf = (const float*)d_in[1];
    const float* bf = (const float*)d_in[2];
    const float* Wb = (const float*)d_in[3];
    const float* bb = (const float*)d_in[4];
    const float* Wg = (const float*)d_in[5];
    const float* bg = (const float*)d_in[6];
    const int* idx = (const int*)d_in[7];
    float* out = (float*)d_out;

    const int n_edges = in_sizes[7] / 2;

    __hip_bfloat162* node_sum = (__hip_bfloat162*)d_ws;            // N_NODES*32 bf16x2
    float* deg = (float*)((char*)d_ws + (size_t)N_NODES * DIM * 2); // N_NODES f32

    size_t zero_bytes = (size_t)N_NODES * DIM * 2 + (size_t)N_NODES * 4;
    hipMemsetAsync(d_ws, 0, zero_bytes, stream);

    long long sthreads = (long long)n_edges * 32;
    int blocks1 = (int)((sthreads + 255) / 256);
    scatter_kernel<<<blocks1, 256, 0, stream>>>(edge_emb, idx, node_sum, deg, n_edges);

    int blocks2 = 2048;   // 8192 waves, ~7.6 batches/wave: amortizes B-frag preamble
    fused_edge_kernel<<<blocks2, 256, 0, stream>>>(
        edge_emb, idx, (const unsigned short*)node_sum, deg,
        Wf, bf, Wb, bb, Wg, bg, out, n_edges);
}